// Round 1
// baseline (20.651 us; speedup 1.0000x reference)
//
#include <hip/hip_runtime.h>

#define NPTS 1024
#define RES 0.2592f
#define CMIN (319.5f * 0.2592f)   // (640/2 - 0.5) * 0.2592

// One block per batch element. 256 threads, 4 points/thread.
__global__ __launch_bounds__(256) void kabsch_kernel(
    const float* __restrict__ kp,   // (2*B, NPTS, 2) pixel coords; batch b uses row 2b
    const float* __restrict__ tg,   // (B, NPTS, 2)
    const float* __restrict__ wt,   // (B, NPTS)
    float* __restrict__ outR,       // (B, 9)  = R_tgt_src^T row-major
    float* __restrict__ outT)       // (B, 3)  = t_src_tgt_intgt
{
    const int b   = blockIdx.x;
    const int tid = threadIdx.x;

    const float4* wp = (const float4*)(wt + (long)b * NPTS);
    const float4* sp = (const float4*)(kp + (long)(2 * b) * NPTS * 2);
    const float4* tp = (const float4*)(tg + (long)b * NPTS * 2);

    // 4 consecutive points per thread
    float4 w4  = wp[tid];
    float4 s01 = sp[tid * 2];
    float4 s23 = sp[tid * 2 + 1];
    float4 t01 = tp[tid * 2];
    float4 t23 = tp[tid * 2 + 1];

    float acc[9];
#pragma unroll
    for (int i = 0; i < 9; ++i) acc[i] = 0.f;

    float pxs[4] = {s01.x, s01.z, s23.x, s23.z};
    float pys[4] = {s01.y, s01.w, s23.y, s23.w};
    float qxs[4] = {t01.x, t01.z, t23.x, t23.z};
    float qys[4] = {t01.y, t01.w, t23.y, t23.w};
    float ws[4]  = {w4.x, w4.y, w4.z, w4.w};

#pragma unroll
    for (int k = 0; k < 4; ++k) {
        // radar-frame transform
        float sx = CMIN - RES * pys[k];
        float sy = RES * pxs[k] - CMIN;
        float tx = CMIN - RES * qys[k];
        float ty = RES * qxs[k] - CMIN;
        float w  = ws[k];
        float wtx = w * tx;
        float wty = w * ty;
        acc[0] += w;
        acc[1] += w * sx;
        acc[2] += w * sy;
        acc[3] += wtx;
        acc[4] += wty;
        acc[5] += wtx * sx;
        acc[6] += wtx * sy;
        acc[7] += wty * sx;
        acc[8] += wty * sy;
    }

    // wave (64-lane) butterfly reduce
#pragma unroll
    for (int i = 0; i < 9; ++i) {
#pragma unroll
        for (int off = 32; off >= 1; off >>= 1)
            acc[i] += __shfl_xor(acc[i], off, 64);
    }

    __shared__ float red[4][9];
    const int wave = tid >> 6;
    const int lane = tid & 63;
    if (lane == 0) {
#pragma unroll
        for (int i = 0; i < 9; ++i) red[wave][i] = acc[i];
    }
    __syncthreads();

    if (tid == 0) {
        float s[9];
#pragma unroll
        for (int i = 0; i < 9; ++i)
            s[i] = red[0][i] + red[1][i] + red[2][i] + red[3][i];

        const float Sw  = s[0];
        const float Ssx = s[1], Ssy = s[2];
        const float Stx = s[3], Sty = s[4];
        const float M00 = s[5], M01 = s[6], M10 = s[7], M11 = s[8];

        // W2 * Sw^2 (positive scale irrelevant for polar factor)
        const float a  = M00 * Sw - Stx * Ssx;
        const float bb = M01 * Sw - Stx * Ssy;
        const float c  = M10 * Sw - Sty * Ssx;
        const float d  = M11 * Sw - Sty * Ssy;
        const float det = a * d - bb * c;

        float Q00, Q01, Q10, Q11, sgn;
        if (det >= 0.f) {
            float p = a + d, q = c - bb;
            float h = rsqrtf(p * p + q * q);
            p *= h; q *= h;
            Q00 = p;  Q01 = -q;
            Q10 = q;  Q11 = p;
            sgn = 1.f;
        } else {
            float p = a - d, q = bb + c;
            float h = rsqrtf(p * p + q * q);
            p *= h; q *= h;
            Q00 = p;  Q01 = q;
            Q10 = q;  Q11 = -p;
            sgn = -1.f;
        }

        const float inv = 1.f / Sw;
        const float sbx = Ssx * inv, sby = Ssy * inv;
        const float tbx = Stx * inv, tby = Sty * inv;

        // t1 = src_centroid - R^T * tgt_centroid
        const float t1x = sbx - (Q00 * tbx + Q10 * tby);
        const float t1y = sby - (Q01 * tbx + Q11 * tby);
        // t2 = -R * t1
        const float t2x = -(Q00 * t1x + Q01 * t1y);
        const float t2y = -(Q10 * t1x + Q11 * t1y);

        // output 0: R^T row-major = [[Q00,Q10,0],[Q01,Q11,0],[0,0,sgn]]
        float* r = outR + (long)b * 9;
        r[0] = Q00; r[1] = Q10; r[2] = 0.f;
        r[3] = Q01; r[4] = Q11; r[5] = 0.f;
        r[6] = 0.f; r[7] = 0.f; r[8] = sgn;

        float* t = outT + (long)b * 3;
        t[0] = t2x; t[1] = t2y; t[2] = 0.f;
    }
}

extern "C" void kernel_launch(void* const* d_in, const int* in_sizes, int n_in,
                              void* d_out, int out_size, void* d_ws, size_t ws_size,
                              hipStream_t stream) {
    const float* kp = (const float*)d_in[0];  // (8192, 1024, 2)
    const float* tg = (const float*)d_in[1];  // (4096, 1024, 2)
    const float* wt = (const float*)d_in[2];  // (4096, 1024)

    const int B = in_sizes[2] / NPTS;         // 4096
    float* outR = (float*)d_out;              // B*9
    float* outT = (float*)d_out + (long)B * 9;

    kabsch_kernel<<<B, 256, 0, stream>>>(kp, tg, wt, outR, outT);
}

// Round 2
// 20.379 us; speedup vs baseline: 1.0134x; 1.0134x over previous
//
#include <hip/hip_runtime.h>

#define NPTS 1024
#define RES 0.2592f
#define CMIN (319.5f * 0.2592f)   // (640/2 - 0.5) * 0.2592

// One WAVE per batch element. 256 threads = 4 waves = 4 batches per block.
// Grid = B/4 = 1024 blocks -> 4 blocks/CU co-resident.
__global__ __launch_bounds__(256, 4) void kabsch_kernel(
    const float* __restrict__ kp,   // (2*B, NPTS, 2) pixel coords; batch b uses row 2b
    const float* __restrict__ tg,   // (B, NPTS, 2)
    const float* __restrict__ wt,   // (B, NPTS)
    float* __restrict__ outR,       // (B, 9)  = R_tgt_src^T row-major
    float* __restrict__ outT)       // (B, 3)  = t_src_tgt_intgt
{
    const int wave = threadIdx.x >> 6;
    const int lane = threadIdx.x & 63;
    const int b    = blockIdx.x * 4 + wave;

    const float2* wp = (const float2*)(wt + (long)b * NPTS);
    const float4* sp = (const float4*)(kp + (long)(2 * b) * NPTS * 2);
    const float4* tp = (const float4*)(tg + (long)b * NPTS * 2);

    float acc[9];
#pragma unroll
    for (int i = 0; i < 9; ++i) acc[i] = 0.f;

    // 8 coalesced chunks: float4 covers 2 points; float2 covers their 2 weights.
#pragma unroll
    for (int c = 0; c < 8; ++c) {
        const int idx = lane + 64 * c;
        float4 s4 = sp[idx];
        float4 t4 = tp[idx];
        float2 w2 = wp[idx];

#pragma unroll
        for (int k = 0; k < 2; ++k) {
            float px = k ? s4.z : s4.x;
            float py = k ? s4.w : s4.y;
            float qx = k ? t4.z : t4.x;
            float qy = k ? t4.w : t4.y;
            float w  = k ? w2.y : w2.x;

            // radar-frame transform
            float sx = CMIN - RES * py;
            float sy = RES * px - CMIN;
            float tx = CMIN - RES * qy;
            float ty = RES * qx - CMIN;
            float wtx = w * tx;
            float wty = w * ty;
            acc[0] += w;
            acc[1] += w * sx;
            acc[2] += w * sy;
            acc[3] += wtx;
            acc[4] += wty;
            acc[5] += wtx * sx;
            acc[6] += wtx * sy;
            acc[7] += wty * sx;
            acc[8] += wty * sy;
        }
    }

    // single 64-lane butterfly reduce per batch
#pragma unroll
    for (int i = 0; i < 9; ++i) {
#pragma unroll
        for (int off = 32; off >= 1; off >>= 1)
            acc[i] += __shfl_xor(acc[i], off, 64);
    }

    if (lane == 0) {
        const float Sw  = acc[0];
        const float Ssx = acc[1], Ssy = acc[2];
        const float Stx = acc[3], Sty = acc[4];
        const float M00 = acc[5], M01 = acc[6], M10 = acc[7], M11 = acc[8];

        // W2 * Sw^2 (positive scale irrelevant for the polar factor)
        const float a  = M00 * Sw - Stx * Ssx;
        const float bb = M01 * Sw - Stx * Ssy;
        const float c  = M10 * Sw - Sty * Ssx;
        const float d  = M11 * Sw - Sty * Ssy;
        const float det = a * d - bb * c;

        float Q00, Q01, Q10, Q11, sgn;
        if (det >= 0.f) {
            float p = a + d, q = c - bb;
            float h = rsqrtf(p * p + q * q);
            p *= h; q *= h;
            Q00 = p;  Q01 = -q;
            Q10 = q;  Q11 = p;
            sgn = 1.f;
        } else {
            float p = a - d, q = bb + c;
            float h = rsqrtf(p * p + q * q);
            p *= h; q *= h;
            Q00 = p;  Q01 = q;
            Q10 = q;  Q11 = -p;
            sgn = -1.f;
        }

        const float inv = 1.f / Sw;
        const float sbx = Ssx * inv, sby = Ssy * inv;
        const float tbx = Stx * inv, tby = Sty * inv;

        // t1 = src_centroid - R^T * tgt_centroid
        const float t1x = sbx - (Q00 * tbx + Q10 * tby);
        const float t1y = sby - (Q01 * tbx + Q11 * tby);
        // t2 = -R * t1
        const float t2x = -(Q00 * t1x + Q01 * t1y);
        const float t2y = -(Q10 * t1x + Q11 * t1y);

        // output 0: R^T row-major = [[Q00,Q10,0],[Q01,Q11,0],[0,0,sgn]]
        float* r = outR + (long)b * 9;
        r[0] = Q00; r[1] = Q10; r[2] = 0.f;
        r[3] = Q01; r[4] = Q11; r[5] = 0.f;
        r[6] = 0.f; r[7] = 0.f; r[8] = sgn;

        float* t = outT + (long)b * 3;
        t[0] = t2x; t[1] = t2y; t[2] = 0.f;
    }
}

extern "C" void kernel_launch(void* const* d_in, const int* in_sizes, int n_in,
                              void* d_out, int out_size, void* d_ws, size_t ws_size,
                              hipStream_t stream) {
    const float* kp = (const float*)d_in[0];  // (8192, 1024, 2)
    const float* tg = (const float*)d_in[1];  // (4096, 1024, 2)
    const float* wt = (const float*)d_in[2];  // (4096, 1024)

    const int B = in_sizes[2] / NPTS;         // 4096
    float* outR = (float*)d_out;              // B*9
    float* outT = (float*)d_out + (long)B * 9;

    kabsch_kernel<<<B / 4, 256, 0, stream>>>(kp, tg, wt, outR, outT);
}